// Round 6
// baseline (217.773 us; speedup 1.0000x reference)
//
#include <hip/hip_runtime.h>
#include <hip/hip_bf16.h>

typedef __attribute__((ext_vector_type(8))) __bf16 bf16x8;
typedef __attribute__((ext_vector_type(8))) short short8;
typedef __attribute__((ext_vector_type(4))) float f32x4;
typedef __attribute__((ext_vector_type(16))) float f32x16;
typedef __attribute__((ext_vector_type(4))) short sh4;

typedef __attribute__((address_space(1))) void GVoid;
typedef __attribute__((address_space(3))) void LVoid;

#define NEGBIG (-1e30f)
#define SCL 0.18033688011112042f   // 0.125 * log2(e): folded into Q at GEMM1 epilogue

constexpr int TT = 2048, CC = 1024, HH = 16, DD = 64, C3 = 3072;

__device__ __forceinline__ unsigned short f2bf(float f) {   // RNE
  unsigned int i = __float_as_uint(f);
  return (unsigned short)((i + 0x7FFFu + ((i >> 16) & 1u)) >> 16);
}
__device__ __forceinline__ void async16(const void* g, void* l) {
  __builtin_amdgcn_global_load_lds((GVoid*)g, (LVoid*)l, 16, 0, 0);
}

// ---------- pre-pass: fp32 -> bf16 elementwise convert ----------
__global__ __launch_bounds__(256) void cvt_bf16(
    const float* __restrict__ in, unsigned short* __restrict__ out, int n8)
{
  const int i = blockIdx.x * 256 + threadIdx.x;
  if (i >= n8) return;
  const float* p = in + (size_t)i * 8;
  f32x4 a = *(const f32x4*)p, b = *(const f32x4*)(p + 4);
  sh4 r0, r1;
  ((unsigned short*)&r0)[0] = f2bf(a[0]); ((unsigned short*)&r0)[1] = f2bf(a[1]);
  ((unsigned short*)&r0)[2] = f2bf(a[2]); ((unsigned short*)&r0)[3] = f2bf(a[3]);
  ((unsigned short*)&r1)[0] = f2bf(b[0]); ((unsigned short*)&r1)[1] = f2bf(b[1]);
  ((unsigned short*)&r1)[2] = f2bf(b[2]); ((unsigned short*)&r1)[3] = f2bf(b[3]);
  *(sh4*)(out + (size_t)i * 8) = r0;
  *(sh4*)(out + (size_t)i * 8 + 4) = r1;
}

// ---------- pre-pass: transpose + convert: fp32 in[R][Cd] -> bf16 out[Cd][R] ----------
__global__ __launch_bounds__(256) void transpose_cvt(
    const float* __restrict__ in, unsigned short* __restrict__ out, int R, int Cd)
{
  __shared__ __align__(16) unsigned short tile[64 * 72];
  const int r0 = blockIdx.y * 64, c0 = blockIdx.x * 64;
  const int tid = threadIdx.x;
#pragma unroll
  for (int r = 0; r < 2; ++r) {
    const int elem = r * 2048 + tid * 8;
    const int ii = elem >> 6, jj = elem & 63;
    const float* p = in + (size_t)(r0 + ii) * Cd + c0 + jj;
    f32x4 a = *(const f32x4*)p, b = *(const f32x4*)(p + 4);
    short8 v;
    ((unsigned short*)&v)[0] = f2bf(a[0]); ((unsigned short*)&v)[1] = f2bf(a[1]);
    ((unsigned short*)&v)[2] = f2bf(a[2]); ((unsigned short*)&v)[3] = f2bf(a[3]);
    ((unsigned short*)&v)[4] = f2bf(b[0]); ((unsigned short*)&v)[5] = f2bf(b[1]);
    ((unsigned short*)&v)[6] = f2bf(b[2]); ((unsigned short*)&v)[7] = f2bf(b[3]);
    *(short8*)&tile[ii * 72 + jj] = v;
  }
  __syncthreads();
#pragma unroll
  for (int r = 0; r < 2; ++r) {
    const int elem = r * 2048 + tid * 8;
    const int jj = elem >> 6, ii0 = elem & 63;
    short8 v;
#pragma unroll
    for (int e = 0; e < 8; ++e) ((unsigned short*)&v)[e] = tile[(ii0 + e) * 72 + jj];
    *(short8*)&out[(size_t)(c0 + jj) * R + r0 + ii0] = v;
  }
}

// ---------------- GEMM (m97 structure), 128x128 tile ----------------
// MODE 0 (QKV): gn<1024 -> Q*SCL bf16; 1024..2047 -> K bf16; >=2048 -> Vt transposed
//   (V stores PACKED: 4 acc g-values are consecutive in t -> one 8-B store/lane).
// MODE 1 (proj): C fp32.
template <int MODE>
__global__ __launch_bounds__(256) void gemm_bt(
    const unsigned short* __restrict__ A,
    const unsigned short* __restrict__ Bt,
    const float* __restrict__ bias,
    void* __restrict__ Cp, unsigned short* __restrict__ Vt,
    int M, int N, int K, int lda)
{
  __shared__ __align__(16) unsigned short sA[128 * 32];
  __shared__ __align__(16) unsigned short sB[128 * 32];
  const int tid = threadIdx.x;
  const int w = tid >> 6, l = tid & 63, ln = l & 15, quad = l >> 4;
  const int wm = w >> 1, wn = w & 1;
  const int m0 = blockIdx.y * 128, n0 = blockIdx.x * 128;
  f32x4 acc[4][4] = {};

  for (int k0 = 0; k0 < K; k0 += 32) {
    __syncthreads();
#pragma unroll
    for (int r = 0; r < 2; ++r) {
      const int elem = r * 2048 + tid * 8;
      const int ar = elem >> 5, ac = elem & 31;
      async16(A  + (size_t)(m0 + ar) * lda + k0 + ac, sA + r * 2048 + w * 512);
      async16(Bt + (size_t)(n0 + ar) * K   + k0 + ac, sB + r * 2048 + w * 512);
    }
    __syncthreads();

    bf16x8 af[4], bfr[4];
#pragma unroll
    for (int i = 0; i < 4; i++)
      af[i] = *(const bf16x8*)&sA[(wm * 64 + i * 16 + ln) * 32 + quad * 8];
#pragma unroll
    for (int j = 0; j < 4; j++)
      bfr[j] = *(const bf16x8*)&sB[(wn * 64 + j * 16 + ln) * 32 + quad * 8];
#pragma unroll
    for (int i = 0; i < 4; i++)
#pragma unroll
      for (int j = 0; j < 4; j++)
        acc[i][j] = __builtin_amdgcn_mfma_f32_16x16x32_bf16(af[i], bfr[j], acc[i][j], 0, 0, 0);
  }

  float bj[4];
#pragma unroll
  for (int j = 0; j < 4; j++) bj[j] = bias[n0 + wn * 64 + j * 16 + ln];

#pragma unroll
  for (int i = 0; i < 4; i++) {
#pragma unroll
    for (int j = 0; j < 4; j++) {
      const int gn = n0 + wn * 64 + j * 16 + ln;
      if (MODE == 0 && gn >= 2048) {                 // V: pack g-quad -> one 8B store
        const int hh = (gn >> 6) & 15, dd = gn & 63;
        const int gm0 = m0 + wm * 64 + i * 16 + quad * 4;
        const int bb = gm0 >> 11, t0 = gm0 & 2047;   // g-quad never crosses batch
        sh4 rv;
#pragma unroll
        for (int g = 0; g < 4; ++g)
          ((unsigned short*)&rv)[g] = f2bf(acc[i][j][g] + bj[j]);
        *(sh4*)&Vt[((size_t)((bb * HH + hh) * DD + dd)) * TT + t0] = rv;
      } else {
#pragma unroll
        for (int g = 0; g < 4; ++g) {
          const int gm = m0 + wm * 64 + i * 16 + quad * 4 + g;
          float v = acc[i][j][g] + bj[j];
          if (MODE == 0) {
            if (gn < 1024) v *= SCL;   // fold softmax scale into Q (pre-round: free)
            ((unsigned short*)Cp)[(size_t)gm * 2048 + gn] = f2bf(v);
          } else {
            ((float*)Cp)[(size_t)gm * N + gn] = v;
          }
        }
      }
    }
  }
}

// ---------------- GEMM, 128x64 tile (proj: 512 blocks = 2/CU) ----------------
__global__ __launch_bounds__(256) void gemm_n64(
    const unsigned short* __restrict__ A,
    const unsigned short* __restrict__ Bt,
    const float* __restrict__ bias,
    float* __restrict__ Cp, int M, int N, int K, int lda)
{
  __shared__ __align__(16) unsigned short sA[128 * 32];
  __shared__ __align__(16) unsigned short sB[64 * 32];
  const int tid = threadIdx.x;
  const int w = tid >> 6, l = tid & 63, ln = l & 15, quad = l >> 4;
  const int wm = w >> 1, wn = w & 1;
  const int m0 = blockIdx.y * 128, n0 = blockIdx.x * 64;
  f32x4 acc[4][2] = {};

  for (int k0 = 0; k0 < K; k0 += 32) {
    __syncthreads();
#pragma unroll
    for (int r = 0; r < 2; ++r) {
      const int elem = r * 2048 + tid * 8;
      const int ar = elem >> 5, ac = elem & 31;
      async16(A + (size_t)(m0 + ar) * lda + k0 + ac, sA + r * 2048 + w * 512);
    }
    {
      const int elem = tid * 8;
      const int ar = elem >> 5, ac = elem & 31;
      async16(Bt + (size_t)(n0 + ar) * K + k0 + ac, sB + w * 512);
    }
    __syncthreads();

    bf16x8 af[4], bfr[2];
#pragma unroll
    for (int i = 0; i < 4; i++)
      af[i] = *(const bf16x8*)&sA[(wm * 64 + i * 16 + ln) * 32 + quad * 8];
#pragma unroll
    for (int j = 0; j < 2; j++)
      bfr[j] = *(const bf16x8*)&sB[(wn * 32 + j * 16 + ln) * 32 + quad * 8];
#pragma unroll
    for (int i = 0; i < 4; i++)
#pragma unroll
      for (int j = 0; j < 2; j++)
        acc[i][j] = __builtin_amdgcn_mfma_f32_16x16x32_bf16(af[i], bfr[j], acc[i][j], 0, 0, 0);
  }

  float bj[2];
#pragma unroll
  for (int j = 0; j < 2; j++) bj[j] = bias[n0 + wn * 32 + j * 16 + ln];

#pragma unroll
  for (int i = 0; i < 4; i++)
#pragma unroll
    for (int g = 0; g < 4; ++g) {
      const int gm = m0 + wm * 64 + i * 16 + quad * 4 + g;
#pragma unroll
      for (int j = 0; j < 2; j++) {
        const int gn = n0 + wn * 32 + j * 16 + ln;
        Cp[(size_t)gm * N + gn] = acc[i][j][g] + bj[j];
      }
    }
}

// ---------------- Flash attention (causal), D=64, 128-row q-tiles ----------------
// Round-2 SHELL (grid (8,32)=256 blocks=1/CU, {p,15-p} pairing -> uniform 34 iters,
// staged K/V double/triple buffers, PV-lag-1 pipeline, one barrier/iter) with the
// Round-3-VERIFIED math (32x32x16 S^T MFMA + in-register cvt_pk/permlane32_swap
// softmax): 4 waves x 32 q-rows. Why: attn128's per-CU-iter cost was dominated by
// the LDS pipe (~3300/3900 cy: 144 b128 reads + 128 pt b16 writes + conflicts).
// This version serves the SAME 128 q-rows x 64 keys per iter with 64 b128 reads
// (round-3-measured ZERO bank conflicts on this exact stride-144B pattern) and no
// pt at all. pt LDS round-trip -> VALU cvt_pk/permlane (pipe with headroom).
// STATIC softmax (scores bounded, Q pre-scaled, log2 domain). LDS 46KB.
__global__ __launch_bounds__(256) void attn32q(
    unsigned short* __restrict__ QK, const unsigned short* __restrict__ Vt)
{
  __shared__ __align__(16) unsigned short kt[2][64 * 72];   // [key][d]
  __shared__ __align__(16) unsigned short vt[3][64 * 72];   // [d][key] rotating
  const int pair = blockIdx.x, bh = blockIdx.y;
  const int b = bh >> 4, h = bh & 15;
  const int tid = threadIdx.x, w = tid >> 6, l = tid & 63;
  const int c = l & 31, h2 = l >> 5;
  unsigned short*       Qp = QK + (size_t)b * TT * 2048 + h * DD;
  const unsigned short* Kp = QK + (size_t)b * TT * 2048 + CC + h * DD;
  const unsigned short* Vh = Vt + (size_t)bh * DD * TT;
  const int si0 = tid >> 3, so = (tid & 7) * 8;             // 2 passes cover 64x64

  for (int ph = 0; ph < 2; ++ph) {
    const int qt = ph ? 15 - pair : pair;
    const int qbase = qt * 128 + w * 32;                    // wave's first q-row
    const int qm = qbase + c - 4 * h2;                      // mask helper (r3-verified)
    bf16x8 qv[4];
#pragma unroll
    for (int ds = 0; ds < 4; ++ds)                          // Q B-operand frags
      qv[ds] = *(const bf16x8*)&Qp[(size_t)(qbase + c) * 2048 + ds * 16 + h2 * 8];

    f32x16 oacc[2] = {};
    bf16x8 pA[4] = {};
    float lsum = 0.0f;
    const int kbmax = 2 * qt + 1;
    int vm1 = 2, v0 = 0, vp1 = 1;                           // (kb-1,kb,kb+1) % 3

    __syncthreads();                                        // prior phase reads done
#pragma unroll
    for (int r = 0; r < 2; ++r) {                           // stage kb=0 -> buffer 0
      const int si = si0 + 32 * r;
      *(short8*)&kt[0][si * 72 + so] = *(const short8*)&Kp[(size_t)si * 2048 + so];
      *(short8*)&vt[0][si * 72 + so] = *(const short8*)&Vh[(size_t)si * TT + so];
    }
    __syncthreads();                                        // buf0 visible

    for (int kb = 0; kb <= kbmax; ++kb) {
      const int ck = kb & 1;
      short8 pk[2], pv[2];
      if (kb < kbmax) {                                     // prefetch kb+1 -> regs
#pragma unroll
        for (int r = 0; r < 2; ++r) {
          const int si = si0 + 32 * r;
          pk[r] = *(const short8*)&Kp[(size_t)((kb + 1) * 64 + si) * 2048 + so];
          pv[r] = *(const short8*)&Vh[(size_t)si * TT + (kb + 1) * 64 + so];
        }
      }
      const bool qk_act = (kb * 64 <= qbase + 31);          // wave-uniform
      f32x16 sacc[2];
      if (qk_act) {                                         // S^T(kb) = K * Q^T
#pragma unroll
        for (int kg = 0; kg < 2; ++kg) {
          f32x16 sa = {};
#pragma unroll
          for (int ds = 0; ds < 4; ++ds) {
            bf16x8 kf = *(const bf16x8*)&kt[ck][(kg * 32 + c) * 72 + ds * 16 + h2 * 8];
            sa = __builtin_amdgcn_mfma_f32_32x32x16_bf16(kf, qv[ds], sa, 0, 0, 0);
          }
          sacc[kg] = sa;
        }
      }
      if (kb > 0 && (kb - 1) * 64 <= qbase + 31) {          // PV(kb-1): independent,
        const unsigned short* vp = vt[vm1];                 // overlaps softmax chain
#pragma unroll
        for (int dg = 0; dg < 2; ++dg)
#pragma unroll
          for (int ks = 0; ks < 4; ++ks) {
            bf16x8 vf = *(const bf16x8*)&vp[(dg * 32 + c) * 72 + ks * 16 + h2 * 8];
            oacc[dg] = __builtin_amdgcn_mfma_f32_32x32x16_bf16(pA[ks], vf, oacc[dg], 0, 0, 0);
          }
      }
      if (qk_act) {
        const bool need_mask = (kb * 64 + 63 > qbase);      // diagonal tile only
        float pe[2][16];
#pragma unroll
        for (int kg = 0; kg < 2; ++kg)
#pragma unroll
          for (int rr = 0; rr < 16; ++rr) {
            float sv = sacc[kg][rr];
            if (need_mask) {
              const int krel = kb * 64 + kg * 32 + (rr & 3) + 8 * (rr >> 2);
              if (krel > qm) sv = NEGBIG;                   // key > q -> masked
            }
            const float e = exp2f(sv);
            pe[kg][rr] = e;
            lsum += e;
          }
        // pack P^T pairs to bf16, redistribute to PV A-frags (round-3-verified)
        unsigned W0[2][4], W1[2][4];
#pragma unroll
        for (int kg = 0; kg < 2; ++kg)
#pragma unroll
          for (int r4 = 0; r4 < 4; ++r4) {
            asm("v_cvt_pk_bf16_f32 %0, %1, %2"
                : "=v"(W0[kg][r4]) : "v"(pe[kg][4 * r4 + 0]), "v"(pe[kg][4 * r4 + 1]));
            asm("v_cvt_pk_bf16_f32 %0, %1, %2"
                : "=v"(W1[kg][r4]) : "v"(pe[kg][4 * r4 + 2]), "v"(pe[kg][4 * r4 + 3]));
          }
#pragma unroll
        for (int ks = 0; ks < 4; ++ks) {
          const int kg = ks >> 1, sel = ks & 1;
          unsigned a0 = W0[kg][2 * sel], b0 = W0[kg][2 * sel + 1];
          unsigned a1 = W1[kg][2 * sel], b1 = W1[kg][2 * sel + 1];
          asm("v_permlane32_swap_b32 %0, %1" : "+v"(a0), "+v"(b0));
          asm("v_permlane32_swap_b32 %0, %1" : "+v"(a1), "+v"(b1));
          unsigned wds[4] = {a0, a1, b0, b1};               // keys e01,e23,e45,e67
          pA[ks] = *(const bf16x8*)wds;
        }
      }
      if (kb < kbmax) {                                     // stage kb+1
#pragma unroll
        for (int r = 0; r < 2; ++r) {
          const int si = si0 + 32 * r;
          *(short8*)&kt[1 - ck][si * 72 + so] = pk[r];
          *(short8*)&vt[vp1][si * 72 + so] = pv[r];
        }
      }
      __syncthreads();                                      // one barrier per iter
      const int t_ = vm1; vm1 = v0; v0 = vp1; vp1 = t_;     // rotate V buffers
    }
    // drain: PV(kbmax) for waves whose last k-tile is kbmax (w=2,3)
    if (kbmax * 64 <= qbase + 31) {
      const unsigned short* vp = vt[vm1];                   // vm1 == kbmax % 3
#pragma unroll
      for (int dg = 0; dg < 2; ++dg)
#pragma unroll
        for (int ks = 0; ks < 4; ++ks) {
          bf16x8 vf = *(const bf16x8*)&vp[(dg * 32 + c) * 72 + ks * 16 + h2 * 8];
          oacc[dg] = __builtin_amdgcn_mfma_f32_32x32x16_bf16(pA[ks], vf, oacc[dg], 0, 0, 0);
        }
    }
    // epilogue: l across halves, normalize, store O (in place of Q)
    lsum += __shfl_xor(lsum, 32);
    const float inv = 1.0f / lsum;                          // valid for q=c, all lanes
#pragma unroll
    for (int rr = 0; rr < 16; ++rr) {
      const int q_rel = (rr & 3) + 8 * (rr >> 2) + 4 * h2;
      const float iq = __shfl(inv, q_rel);
      const size_t trow = qbase + q_rel;
#pragma unroll
      for (int dg = 0; dg < 2; ++dg)
        Qp[trow * 2048 + dg * 32 + c] = f2bf(oacc[dg][rr] * iq);
    }
  }
}

extern "C" void kernel_launch(void* const* d_in, const int* in_sizes, int n_in,
                              void* d_out, int out_size, void* d_ws, size_t ws_size,
                              hipStream_t stream)
{
  (void)in_sizes; (void)n_in; (void)out_size; (void)ws_size;
  const float* x     = (const float*)d_in[0];   // [B,T,C] fp32
  const float* Wqkv  = (const float*)d_in[1];   // [C,3C]
  const float* bqkv  = (const float*)d_in[2];   // [3C]
  const float* Wproj = (const float*)d_in[3];   // [C,C]
  const float* bproj = (const float*)d_in[4];   // [C]

  unsigned short* QK     = (unsigned short*)d_ws;            // [4096][2048] bf16, 16 MB
  unsigned short* WqkvT  = QK + (size_t)4096 * 2048;         // [3072][1024] bf16, 6 MB
  unsigned short* WprojT = WqkvT;                            // aliases (after GEMM1)
  unsigned short* Vt = (unsigned short*)d_out;               // scratch in d_out, 8 MB
  unsigned short* xb = Vt + (size_t)32 * 64 * 2048;          // scratch in d_out, 8 MB

  cvt_bf16<<<dim3(4096 * 1024 / 8 / 256), 256, 0, stream>>>(x, xb, 4096 * 1024 / 8);
  transpose_cvt<<<dim3(C3 / 64, CC / 64), 256, 0, stream>>>(Wqkv, WqkvT, CC, C3);
  gemm_bt<0><<<dim3(C3 / 128, 4096 / 128), 256, 0, stream>>>(
      xb, WqkvT, bqkv, QK, Vt, 4096, C3, CC, CC);
  transpose_cvt<<<dim3(CC / 64, CC / 64), 256, 0, stream>>>(Wproj, WprojT, CC, CC);
  attn32q<<<dim3(8, 2 * HH), 256, 0, stream>>>(QK, Vt);
  gemm_n64<<<dim3(CC / 64, 4096 / 128), 256, 0, stream>>>(
      QK, WprojT, bproj, (float*)d_out, 4096, CC, CC, 2048);
}

// Round 7
// 185.680 us; speedup vs baseline: 1.1728x; 1.1728x over previous
//
#include <hip/hip_runtime.h>
#include <hip/hip_bf16.h>

typedef __attribute__((ext_vector_type(8))) __bf16 bf16x8;
typedef __attribute__((ext_vector_type(8))) short short8;
typedef __attribute__((ext_vector_type(4))) float f32x4;
typedef __attribute__((ext_vector_type(16))) float f32x16;
typedef __attribute__((ext_vector_type(4))) short sh4;

typedef __attribute__((address_space(1))) void GVoid;
typedef __attribute__((address_space(3))) void LVoid;

#define NEGBIG (-1e30f)
#define SCL 0.18033688011112042f   // 0.125 * log2(e): folded into Q at GEMM1 epilogue

constexpr int TT = 2048, CC = 1024, HH = 16, DD = 64, C3 = 3072;

__device__ __forceinline__ unsigned short f2bf(float f) {   // RNE
  unsigned int i = __float_as_uint(f);
  return (unsigned short)((i + 0x7FFFu + ((i >> 16) & 1u)) >> 16);
}
__device__ __forceinline__ void async16(const void* g, void* l) {
  __builtin_amdgcn_global_load_lds((GVoid*)g, (LVoid*)l, 16, 0, 0);
}

// ---------- pre-pass: fp32 -> bf16 elementwise convert ----------
__global__ __launch_bounds__(256) void cvt_bf16(
    const float* __restrict__ in, unsigned short* __restrict__ out, int n8)
{
  const int i = blockIdx.x * 256 + threadIdx.x;
  if (i >= n8) return;
  const float* p = in + (size_t)i * 8;
  f32x4 a = *(const f32x4*)p, b = *(const f32x4*)(p + 4);
  sh4 r0, r1;
  ((unsigned short*)&r0)[0] = f2bf(a[0]); ((unsigned short*)&r0)[1] = f2bf(a[1]);
  ((unsigned short*)&r0)[2] = f2bf(a[2]); ((unsigned short*)&r0)[3] = f2bf(a[3]);
  ((unsigned short*)&r1)[0] = f2bf(b[0]); ((unsigned short*)&r1)[1] = f2bf(b[1]);
  ((unsigned short*)&r1)[2] = f2bf(b[2]); ((unsigned short*)&r1)[3] = f2bf(b[3]);
  *(sh4*)(out + (size_t)i * 8) = r0;
  *(sh4*)(out + (size_t)i * 8 + 4) = r1;
}

// ---------- pre-pass: transpose + convert: fp32 in[R][Cd] -> bf16 out[Cd][R] ----------
__global__ __launch_bounds__(256) void transpose_cvt(
    const float* __restrict__ in, unsigned short* __restrict__ out, int R, int Cd)
{
  __shared__ __align__(16) unsigned short tile[64 * 72];
  const int r0 = blockIdx.y * 64, c0 = blockIdx.x * 64;
  const int tid = threadIdx.x;
#pragma unroll
  for (int r = 0; r < 2; ++r) {
    const int elem = r * 2048 + tid * 8;
    const int ii = elem >> 6, jj = elem & 63;
    const float* p = in + (size_t)(r0 + ii) * Cd + c0 + jj;
    f32x4 a = *(const f32x4*)p, b = *(const f32x4*)(p + 4);
    short8 v;
    ((unsigned short*)&v)[0] = f2bf(a[0]); ((unsigned short*)&v)[1] = f2bf(a[1]);
    ((unsigned short*)&v)[2] = f2bf(a[2]); ((unsigned short*)&v)[3] = f2bf(a[3]);
    ((unsigned short*)&v)[4] = f2bf(b[0]); ((unsigned short*)&v)[5] = f2bf(b[1]);
    ((unsigned short*)&v)[6] = f2bf(b[2]); ((unsigned short*)&v)[7] = f2bf(b[3]);
    *(short8*)&tile[ii * 72 + jj] = v;
  }
  __syncthreads();
#pragma unroll
  for (int r = 0; r < 2; ++r) {
    const int elem = r * 2048 + tid * 8;
    const int jj = elem >> 6, ii0 = elem & 63;
    short8 v;
#pragma unroll
    for (int e = 0; e < 8; ++e) ((unsigned short*)&v)[e] = tile[(ii0 + e) * 72 + jj];
    *(short8*)&out[(size_t)(c0 + jj) * R + r0 + ii0] = v;
  }
}

// ---------------- GEMM (m97 structure), 128x128 tile ----------------
// MODE 0 (QKV): gn<1024 -> Q*SCL bf16; 1024..2047 -> K bf16; >=2048 -> Vt transposed
//   (V stores PACKED: 4 acc g-values are consecutive in t -> one 8-B store/lane).
// MODE 1 (proj): C fp32.
template <int MODE>
__global__ __launch_bounds__(256) void gemm_bt(
    const unsigned short* __restrict__ A,
    const unsigned short* __restrict__ Bt,
    const float* __restrict__ bias,
    void* __restrict__ Cp, unsigned short* __restrict__ Vt,
    int M, int N, int K, int lda)
{
  __shared__ __align__(16) unsigned short sA[128 * 32];
  __shared__ __align__(16) unsigned short sB[128 * 32];
  const int tid = threadIdx.x;
  const int w = tid >> 6, l = tid & 63, ln = l & 15, quad = l >> 4;
  const int wm = w >> 1, wn = w & 1;
  const int m0 = blockIdx.y * 128, n0 = blockIdx.x * 128;
  f32x4 acc[4][4] = {};

  for (int k0 = 0; k0 < K; k0 += 32) {
    __syncthreads();
#pragma unroll
    for (int r = 0; r < 2; ++r) {
      const int elem = r * 2048 + tid * 8;
      const int ar = elem >> 5, ac = elem & 31;
      async16(A  + (size_t)(m0 + ar) * lda + k0 + ac, sA + r * 2048 + w * 512);
      async16(Bt + (size_t)(n0 + ar) * K   + k0 + ac, sB + r * 2048 + w * 512);
    }
    __syncthreads();

    bf16x8 af[4], bfr[4];
#pragma unroll
    for (int i = 0; i < 4; i++)
      af[i] = *(const bf16x8*)&sA[(wm * 64 + i * 16 + ln) * 32 + quad * 8];
#pragma unroll
    for (int j = 0; j < 4; j++)
      bfr[j] = *(const bf16x8*)&sB[(wn * 64 + j * 16 + ln) * 32 + quad * 8];
#pragma unroll
    for (int i = 0; i < 4; i++)
#pragma unroll
      for (int j = 0; j < 4; j++)
        acc[i][j] = __builtin_amdgcn_mfma_f32_16x16x32_bf16(af[i], bfr[j], acc[i][j], 0, 0, 0);
  }

  float bj[4];
#pragma unroll
  for (int j = 0; j < 4; j++) bj[j] = bias[n0 + wn * 64 + j * 16 + ln];

#pragma unroll
  for (int i = 0; i < 4; i++) {
#pragma unroll
    for (int j = 0; j < 4; j++) {
      const int gn = n0 + wn * 64 + j * 16 + ln;
      if (MODE == 0 && gn >= 2048) {                 // V: pack g-quad -> one 8B store
        const int hh = (gn >> 6) & 15, dd = gn & 63;
        const int gm0 = m0 + wm * 64 + i * 16 + quad * 4;
        const int bb = gm0 >> 11, t0 = gm0 & 2047;   // g-quad never crosses batch
        sh4 rv;
#pragma unroll
        for (int g = 0; g < 4; ++g)
          ((unsigned short*)&rv)[g] = f2bf(acc[i][j][g] + bj[j]);
        *(sh4*)&Vt[((size_t)((bb * HH + hh) * DD + dd)) * TT + t0] = rv;
      } else {
#pragma unroll
        for (int g = 0; g < 4; ++g) {
          const int gm = m0 + wm * 64 + i * 16 + quad * 4 + g;
          float v = acc[i][j][g] + bj[j];
          if (MODE == 0) {
            if (gn < 1024) v *= SCL;   // fold softmax scale into Q (pre-round: free)
            ((unsigned short*)Cp)[(size_t)gm * 2048 + gn] = f2bf(v);
          } else {
            ((float*)Cp)[(size_t)gm * N + gn] = v;
          }
        }
      }
    }
  }
}

// ---------------- GEMM, 128x64 tile (proj: 512 blocks = 2/CU) ----------------
__global__ __launch_bounds__(256) void gemm_n64(
    const unsigned short* __restrict__ A,
    const unsigned short* __restrict__ Bt,
    const float* __restrict__ bias,
    float* __restrict__ Cp, int M, int N, int K, int lda)
{
  __shared__ __align__(16) unsigned short sA[128 * 32];
  __shared__ __align__(16) unsigned short sB[64 * 32];
  const int tid = threadIdx.x;
  const int w = tid >> 6, l = tid & 63, ln = l & 15, quad = l >> 4;
  const int wm = w >> 1, wn = w & 1;
  const int m0 = blockIdx.y * 128, n0 = blockIdx.x * 64;
  f32x4 acc[4][2] = {};

  for (int k0 = 0; k0 < K; k0 += 32) {
    __syncthreads();
#pragma unroll
    for (int r = 0; r < 2; ++r) {
      const int elem = r * 2048 + tid * 8;
      const int ar = elem >> 5, ac = elem & 31;
      async16(A + (size_t)(m0 + ar) * lda + k0 + ac, sA + r * 2048 + w * 512);
    }
    {
      const int elem = tid * 8;
      const int ar = elem >> 5, ac = elem & 31;
      async16(Bt + (size_t)(n0 + ar) * K + k0 + ac, sB + w * 512);
    }
    __syncthreads();

    bf16x8 af[4], bfr[2];
#pragma unroll
    for (int i = 0; i < 4; i++)
      af[i] = *(const bf16x8*)&sA[(wm * 64 + i * 16 + ln) * 32 + quad * 8];
#pragma unroll
    for (int j = 0; j < 2; j++)
      bfr[j] = *(const bf16x8*)&sB[(wn * 32 + j * 16 + ln) * 32 + quad * 8];
#pragma unroll
    for (int i = 0; i < 4; i++)
#pragma unroll
      for (int j = 0; j < 2; j++)
        acc[i][j] = __builtin_amdgcn_mfma_f32_16x16x32_bf16(af[i], bfr[j], acc[i][j], 0, 0, 0);
  }

  float bj[2];
#pragma unroll
  for (int j = 0; j < 2; j++) bj[j] = bias[n0 + wn * 32 + j * 16 + ln];

#pragma unroll
  for (int i = 0; i < 4; i++)
#pragma unroll
    for (int g = 0; g < 4; ++g) {
      const int gm = m0 + wm * 64 + i * 16 + quad * 4 + g;
#pragma unroll
      for (int j = 0; j < 2; j++) {
        const int gn = n0 + wn * 32 + j * 16 + ln;
        Cp[(size_t)gm * N + gn] = acc[i][j][g] + bj[j];
      }
    }
}

// ---------------- Flash attention (causal), D=64, 2 parity groups ----------------
// Round-6 post-mortem: attn32q's regression was 1 wave/SIMD (Occupancy 10.9%) --
// nothing hid the per-iter serial chain; and exp2f costs ~15 VALU insts each.
// This kernel: 512 thr = TWO independent 4-wave groups per block, each running the
// verified attn32q machine (32x32 S^T MFMA, in-register cvt_pk/permlane32_swap
// softmax, double/triple-buffered staging, PV-lag-1). Groups split k-tiles by
// PARITY (grp0: even kb, grp1: odd kb) -- additive partials under STATIC softmax
// (merge verified round 4). Both groups active all qt+1 slots, identical barrier
// counts -> 2 waves/SIMD with INDEPENDENT work per SIMD. 17 slots/block (vs 34).
// exp2f -> raw v_exp_f32 (round-4-verified; 2^(-1e30) flushes to 0).
// {p,15-p} pairing -> uniform work; grid (8,32) = 256 blocks = 1/CU. LDS 123KB.
__global__ __launch_bounds__(512) void attn2g(
    unsigned short* __restrict__ QK, const unsigned short* __restrict__ Vt)
{
  __shared__ __align__(16) unsigned short kt[2][2][64 * 72];  // [grp][buf][key][d]
  __shared__ __align__(16) unsigned short vt[2][3][64 * 72];  // [grp][buf][d][key]
  __shared__ float Ox[4][2][16][64];                          // [wg][dg][rr][lane]
  __shared__ float Lx[4][64];
  const int pair = blockIdx.x, bh = blockIdx.y;
  const int b = bh >> 4, h = bh & 15;
  const int tid = threadIdx.x;
  const int grp = tid >> 8, gtid = tid & 255;                 // waves 0-3 / 4-7
  const int wg = (tid >> 6) & 3, l = tid & 63;
  const int c = l & 31, h2 = l >> 5;
  unsigned short*       Qp = QK + (size_t)b * TT * 2048 + h * DD;
  const unsigned short* Kp = QK + (size_t)b * TT * 2048 + CC + h * DD;
  const unsigned short* Vh = Vt + (size_t)bh * DD * TT;
  const int si0 = gtid >> 3, so = (gtid & 7) * 8;             // group stages 64x64

  for (int ph = 0; ph < 2; ++ph) {
    const int qt = ph ? 15 - pair : pair;
    const int qbase = qt * 128 + wg * 32;                     // wave's first q-row
    const int qm = qbase + c - 4 * h2;                        // mask helper (verified)
    bf16x8 qv[4];
#pragma unroll
    for (int ds = 0; ds < 4; ++ds)                            // Q B-operand frags
      qv[ds] = *(const bf16x8*)&Qp[(size_t)(qbase + c) * 2048 + ds * 16 + h2 * 8];

    f32x16 oacc[2] = {};
    bf16x8 pA[4] = {};
    float lsum = 0.0f;
    const int nslot = qt + 1;                                 // tiles per group
    int vm1 = 2, v0 = 0, vp1 = 1;

    __syncthreads();                                          // prior phase done
#pragma unroll
    for (int r = 0; r < 2; ++r) {                             // stage kb=grp -> buf 0
      const int si = si0 + 32 * r;
      *(short8*)&kt[grp][0][si * 72 + so] =
          *(const short8*)&Kp[(size_t)(grp * 64 + si) * 2048 + so];
      *(short8*)&vt[grp][0][si * 72 + so] =
          *(const short8*)&Vh[(size_t)si * TT + grp * 64 + so];
    }
    __syncthreads();                                          // buf0 visible

    for (int slot = 0; slot < nslot; ++slot) {
      const int kb = 2 * slot + grp;                          // this group's tile
      const int ck = slot & 1;
      short8 pk[2], pv[2];
      if (slot + 1 < nslot) {                                 // prefetch kb+2 -> regs
        const int kbn = kb + 2;
#pragma unroll
        for (int r = 0; r < 2; ++r) {
          const int si = si0 + 32 * r;
          pk[r] = *(const short8*)&Kp[(size_t)(kbn * 64 + si) * 2048 + so];
          pv[r] = *(const short8*)&Vh[(size_t)si * TT + kbn * 64 + so];
        }
      }
      const bool qk_act = (kb * 64 <= qbase + 31);            // wave-uniform
      f32x16 sacc[2];
      if (qk_act) {                                           // S^T(kb) = K * Q^T
#pragma unroll
        for (int kg = 0; kg < 2; ++kg) {
          f32x16 sa = {};
#pragma unroll
          for (int ds = 0; ds < 4; ++ds) {
            bf16x8 kf = *(const bf16x8*)&kt[grp][ck][(kg * 32 + c) * 72 + ds * 16 + h2 * 8];
            sa = __builtin_amdgcn_mfma_f32_32x32x16_bf16(kf, qv[ds], sa, 0, 0, 0);
          }
          sacc[kg] = sa;
        }
      }
      if (slot > 0 && (kb - 2) * 64 <= qbase + 31) {          // PV(kb-2), overlaps SM
        const unsigned short* vp = vt[grp][vm1];
#pragma unroll
        for (int dg = 0; dg < 2; ++dg)
#pragma unroll
          for (int ks = 0; ks < 4; ++ks) {
            bf16x8 vf = *(const bf16x8*)&vp[(dg * 32 + c) * 72 + ks * 16 + h2 * 8];
            oacc[dg] = __builtin_amdgcn_mfma_f32_32x32x16_bf16(pA[ks], vf, oacc[dg], 0, 0, 0);
          }
      }
      if (qk_act) {
        const bool need_mask = (kb * 64 + 63 > qbase);        // diagonal tiles only
        float pe[2][16];
#pragma unroll
        for (int kg = 0; kg < 2; ++kg)
#pragma unroll
          for (int rr = 0; rr < 16; ++rr) {
            float sv = sacc[kg][rr];
            if (need_mask) {
              const int krel = kb * 64 + kg * 32 + (rr & 3) + 8 * (rr >> 2);
              if (krel > qm) sv = NEGBIG;                     // key > q -> masked
            }
            float e;
            asm("v_exp_f32 %0, %1" : "=v"(e) : "v"(sv));      // 2^sv; 2^-1e30 = 0
            pe[kg][rr] = e;
            lsum += e;
          }
        // pack P^T pairs to bf16, redistribute to PV A-frags (round-3/4-verified)
        unsigned W0[2][4], W1[2][4];
#pragma unroll
        for (int kg = 0; kg < 2; ++kg)
#pragma unroll
          for (int r4 = 0; r4 < 4; ++r4) {
            asm("v_cvt_pk_bf16_f32 %0, %1, %2"
                : "=v"(W0[kg][r4]) : "v"(pe[kg][4 * r4 + 0]), "v"(pe[kg][4 * r4 + 1]));
            asm("v_cvt_pk_bf16_f32 %0, %1, %2"
                : "=v"(W1[kg][r4]) : "v"(pe[kg][4 * r4 + 2]), "v"(pe[kg][4 * r4 + 3]));
          }
#pragma unroll
        for (int ks = 0; ks < 4; ++ks) {
          const int kg = ks >> 1, sel = ks & 1;
          unsigned a0 = W0[kg][2 * sel], b0 = W0[kg][2 * sel + 1];
          unsigned a1 = W1[kg][2 * sel], b1 = W1[kg][2 * sel + 1];
          asm("v_permlane32_swap_b32 %0, %1" : "+v"(a0), "+v"(b0));
          asm("v_permlane32_swap_b32 %0, %1" : "+v"(a1), "+v"(b1));
          unsigned wds[4] = {a0, a1, b0, b1};                 // keys e01,e23,e45,e67
          pA[ks] = *(const bf16x8*)wds;
        }
      }
      if (slot + 1 < nslot) {                                 // stage kb+2
#pragma unroll
        for (int r = 0; r < 2; ++r) {
          const int si = si0 + 32 * r;
          *(short8*)&kt[grp][1 - ck][si * 72 + so] = pk[r];
          *(short8*)&vt[grp][vp1][si * 72 + so] = pv[r];
        }
      }
      __syncthreads();                                        // one barrier per slot
      const int t_ = vm1; vm1 = v0; v0 = vp1; vp1 = t_;       // rotate V buffers
    }
    // drain: PV of this group's last tile (vm1 == its V after final rotation)
    const int kb_last = 2 * qt + grp;
    if (kb_last * 64 <= qbase + 31) {
      const unsigned short* vp = vt[grp][vm1];
#pragma unroll
      for (int dg = 0; dg < 2; ++dg)
#pragma unroll
        for (int ks = 0; ks < 4; ++ks) {
          bf16x8 vf = *(const bf16x8*)&vp[(dg * 32 + c) * 72 + ks * 16 + h2 * 8];
          oacc[dg] = __builtin_amdgcn_mfma_f32_32x32x16_bf16(pA[ks], vf, oacc[dg], 0, 0, 0);
        }
    }
    // ---- merge the two parity groups (additive partials), normalize, store ----
    lsum += __shfl_xor(lsum, 32);                             // l partial for q=c
    if (grp == 1) {
#pragma unroll
      for (int dg = 0; dg < 2; ++dg)
#pragma unroll
        for (int rr = 0; rr < 16; ++rr) Ox[wg][dg][rr][l] = oacc[dg][rr];
      Lx[wg][l] = lsum;
    }
    __syncthreads();
    if (grp == 0) {
      const float inv = 1.0f / (lsum + Lx[wg][l]);            // valid for q=c
#pragma unroll
      for (int dg = 0; dg < 2; ++dg)
#pragma unroll
        for (int rr = 0; rr < 16; ++rr) oacc[dg][rr] += Ox[wg][dg][rr][l];
#pragma unroll
      for (int rr = 0; rr < 16; ++rr) {
        const int q_rel = (rr & 3) + 8 * (rr >> 2) + 4 * h2;
        const float iq = __shfl(inv, q_rel);
        const size_t trow = qbase + q_rel;
#pragma unroll
        for (int dg = 0; dg < 2; ++dg)
          Qp[trow * 2048 + dg * 32 + c] = f2bf(oacc[dg][rr] * iq);
      }
    }
  }
}

extern "C" void kernel_launch(void* const* d_in, const int* in_sizes, int n_in,
                              void* d_out, int out_size, void* d_ws, size_t ws_size,
                              hipStream_t stream)
{
  (void)in_sizes; (void)n_in; (void)out_size; (void)ws_size;
  const float* x     = (const float*)d_in[0];   // [B,T,C] fp32
  const float* Wqkv  = (const float*)d_in[1];   // [C,3C]
  const float* bqkv  = (const float*)d_in[2];   // [3C]
  const float* Wproj = (const float*)d_in[3];   // [C,C]
  const float* bproj = (const float*)d_in[4];   // [C]

  unsigned short* QK     = (unsigned short*)d_ws;            // [4096][2048] bf16, 16 MB
  unsigned short* WqkvT  = QK + (size_t)4096 * 2048;         // [3072][1024] bf16, 6 MB
  unsigned short* WprojT = WqkvT;                            // aliases (after GEMM1)
  unsigned short* Vt = (unsigned short*)d_out;               // scratch in d_out, 8 MB
  unsigned short* xb = Vt + (size_t)32 * 64 * 2048;          // scratch in d_out, 8 MB

  cvt_bf16<<<dim3(4096 * 1024 / 8 / 256), 256, 0, stream>>>(x, xb, 4096 * 1024 / 8);
  transpose_cvt<<<dim3(C3 / 64, CC / 64), 256, 0, stream>>>(Wqkv, WqkvT, CC, C3);
  gemm_bt<0><<<dim3(C3 / 128, 4096 / 128), 256, 0, stream>>>(
      xb, WqkvT, bqkv, QK, Vt, 4096, C3, CC, CC);
  transpose_cvt<<<dim3(CC / 64, CC / 64), 256, 0, stream>>>(Wproj, WprojT, CC, CC);
  attn2g<<<dim3(8, 2 * HH), 512, 0, stream>>>(QK, Vt);
  gemm_n64<<<dim3(CC / 64, 4096 / 128), 256, 0, stream>>>(
      QK, WprojT, bproj, (float*)d_out, 4096, CC, CC, 2048);
}

// Round 8
// 180.427 us; speedup vs baseline: 1.2070x; 1.0291x over previous
//
#include <hip/hip_runtime.h>
#include <hip/hip_bf16.h>

typedef __attribute__((ext_vector_type(8))) __bf16 bf16x8;
typedef __attribute__((ext_vector_type(8))) short short8;
typedef __attribute__((ext_vector_type(4))) float f32x4;
typedef __attribute__((ext_vector_type(16))) float f32x16;
typedef __attribute__((ext_vector_type(4))) short sh4;

typedef __attribute__((address_space(1))) void GVoid;
typedef __attribute__((address_space(3))) void LVoid;

#define NEGBIG (-1e30f)
#define SCL 0.18033688011112042f   // 0.125 * log2(e): folded into Q at GEMM1 epilogue

constexpr int TT = 2048, CC = 1024, HH = 16, DD = 64, C3 = 3072;

__device__ __forceinline__ unsigned short f2bf(float f) {   // RNE
  unsigned int i = __float_as_uint(f);
  return (unsigned short)((i + 0x7FFFu + ((i >> 16) & 1u)) >> 16);
}
__device__ __forceinline__ void async16(const void* g, void* l) {
  __builtin_amdgcn_global_load_lds((GVoid*)g, (LVoid*)l, 16, 0, 0);
}

// ---------- pre-pass: fp32 -> bf16 elementwise convert ----------
__global__ __launch_bounds__(256) void cvt_bf16(
    const float* __restrict__ in, unsigned short* __restrict__ out, int n8)
{
  const int i = blockIdx.x * 256 + threadIdx.x;
  if (i >= n8) return;
  const float* p = in + (size_t)i * 8;
  f32x4 a = *(const f32x4*)p, b = *(const f32x4*)(p + 4);
  sh4 r0, r1;
  ((unsigned short*)&r0)[0] = f2bf(a[0]); ((unsigned short*)&r0)[1] = f2bf(a[1]);
  ((unsigned short*)&r0)[2] = f2bf(a[2]); ((unsigned short*)&r0)[3] = f2bf(a[3]);
  ((unsigned short*)&r1)[0] = f2bf(b[0]); ((unsigned short*)&r1)[1] = f2bf(b[1]);
  ((unsigned short*)&r1)[2] = f2bf(b[2]); ((unsigned short*)&r1)[3] = f2bf(b[3]);
  *(sh4*)(out + (size_t)i * 8) = r0;
  *(sh4*)(out + (size_t)i * 8 + 4) = r1;
}

// ---------- pre-pass: transpose + convert: fp32 in[R][Cd] -> bf16 out[Cd][R] ----------
__global__ __launch_bounds__(256) void transpose_cvt(
    const float* __restrict__ in, unsigned short* __restrict__ out, int R, int Cd)
{
  __shared__ __align__(16) unsigned short tile[64 * 72];
  const int r0 = blockIdx.y * 64, c0 = blockIdx.x * 64;
  const int tid = threadIdx.x;
#pragma unroll
  for (int r = 0; r < 2; ++r) {
    const int elem = r * 2048 + tid * 8;
    const int ii = elem >> 6, jj = elem & 63;
    const float* p = in + (size_t)(r0 + ii) * Cd + c0 + jj;
    f32x4 a = *(const f32x4*)p, b = *(const f32x4*)(p + 4);
    short8 v;
    ((unsigned short*)&v)[0] = f2bf(a[0]); ((unsigned short*)&v)[1] = f2bf(a[1]);
    ((unsigned short*)&v)[2] = f2bf(a[2]); ((unsigned short*)&v)[3] = f2bf(a[3]);
    ((unsigned short*)&v)[4] = f2bf(b[0]); ((unsigned short*)&v)[5] = f2bf(b[1]);
    ((unsigned short*)&v)[6] = f2bf(b[2]); ((unsigned short*)&v)[7] = f2bf(b[3]);
    *(short8*)&tile[ii * 72 + jj] = v;
  }
  __syncthreads();
#pragma unroll
  for (int r = 0; r < 2; ++r) {
    const int elem = r * 2048 + tid * 8;
    const int jj = elem >> 6, ii0 = elem & 63;
    short8 v;
#pragma unroll
    for (int e = 0; e < 8; ++e) ((unsigned short*)&v)[e] = tile[(ii0 + e) * 72 + jj];
    *(short8*)&out[(size_t)(c0 + jj) * R + r0 + ii0] = v;
  }
}

// ---------------- GEMM, 128x128 tile, single-barrier double-buffered ----------------
// T3-minimum pipeline (guide §5.5): stage tile k+1 into the OTHER LDS buffer
// BEFORE reading/computing tile k; ONE __syncthreads per K-step. Race-free:
// reads of buf X at step k precede step k's barrier; writes to X are issued at
// step k+1 after that barrier; __syncthreads' implicit vmcnt(0) drain makes all
// waves' global_load_lds visible. Load latency overlaps ds_read+MFMA instead of
// serializing behind a stage-barrier (round-7 profile: 1170 cy/step, MfmaUtil 22%).
// MODE 0 (QKV): gn<1024 -> Q*SCL bf16; 1024..2047 -> K bf16; >=2048 -> Vt packed.
// MODE 1 (proj): C fp32.
template <int MODE>
__global__ __launch_bounds__(256) void gemm_bt(
    const unsigned short* __restrict__ A,
    const unsigned short* __restrict__ Bt,
    const float* __restrict__ bias,
    void* __restrict__ Cp, unsigned short* __restrict__ Vt,
    int M, int N, int K, int lda)
{
  __shared__ __align__(16) unsigned short sA[2][128 * 32];
  __shared__ __align__(16) unsigned short sB[2][128 * 32];
  const int tid = threadIdx.x;
  const int w = tid >> 6, l = tid & 63, ln = l & 15, quad = l >> 4;
  const int wm = w >> 1, wn = w & 1;
  const int m0 = blockIdx.y * 128, n0 = blockIdx.x * 128;
  f32x4 acc[4][4] = {};

  const int elem0 = tid * 8;                 // staging coords (constant per thread)
  const int ar0 = elem0 >> 5, ac0 = elem0 & 31;
  const int ar1 = (2048 + elem0) >> 5, ac1 = ac0;

  // prologue: stage k0=0 into buf 0
  async16(A  + (size_t)(m0 + ar0) * lda + ac0, &sA[0][w * 512]);
  async16(Bt + (size_t)(n0 + ar0) * K   + ac0, &sB[0][w * 512]);
  async16(A  + (size_t)(m0 + ar1) * lda + ac1, &sA[0][2048 + w * 512]);
  async16(Bt + (size_t)(n0 + ar1) * K   + ac1, &sB[0][2048 + w * 512]);
  __syncthreads();                           // implicit vmcnt(0) drain: buf0 ready

  int buf = 0;
  for (int k0 = 0; k0 < K; k0 += 32, buf ^= 1) {
    if (k0 + 32 < K) {                       // stage NEXT tile into other buffer
      const int nb = buf ^ 1, kn = k0 + 32;
      async16(A  + (size_t)(m0 + ar0) * lda + kn + ac0, &sA[nb][w * 512]);
      async16(Bt + (size_t)(n0 + ar0) * K   + kn + ac0, &sB[nb][w * 512]);
      async16(A  + (size_t)(m0 + ar1) * lda + kn + ac1, &sA[nb][2048 + w * 512]);
      async16(Bt + (size_t)(n0 + ar1) * K   + kn + ac1, &sB[nb][2048 + w * 512]);
    }

    bf16x8 af[4], bfr[4];
#pragma unroll
    for (int i = 0; i < 4; i++)
      af[i] = *(const bf16x8*)&sA[buf][(wm * 64 + i * 16 + ln) * 32 + quad * 8];
#pragma unroll
    for (int j = 0; j < 4; j++)
      bfr[j] = *(const bf16x8*)&sB[buf][(wn * 64 + j * 16 + ln) * 32 + quad * 8];
#pragma unroll
    for (int i = 0; i < 4; i++)
#pragma unroll
      for (int j = 0; j < 4; j++)
        acc[i][j] = __builtin_amdgcn_mfma_f32_16x16x32_bf16(af[i], bfr[j], acc[i][j], 0, 0, 0);

    __syncthreads();                         // one barrier/K-step: drains next-tile
  }                                          // loads + fences reads of buf

  float bj[4];
#pragma unroll
  for (int j = 0; j < 4; j++) bj[j] = bias[n0 + wn * 64 + j * 16 + ln];

#pragma unroll
  for (int i = 0; i < 4; i++) {
#pragma unroll
    for (int j = 0; j < 4; j++) {
      const int gn = n0 + wn * 64 + j * 16 + ln;
      if (MODE == 0 && gn >= 2048) {                 // V: pack g-quad -> one 8B store
        const int hh = (gn >> 6) & 15, dd = gn & 63;
        const int gm0 = m0 + wm * 64 + i * 16 + quad * 4;
        const int bb = gm0 >> 11, t0 = gm0 & 2047;   // g-quad never crosses batch
        sh4 rv;
#pragma unroll
        for (int g = 0; g < 4; ++g)
          ((unsigned short*)&rv)[g] = f2bf(acc[i][j][g] + bj[j]);
        *(sh4*)&Vt[((size_t)((bb * HH + hh) * DD + dd)) * TT + t0] = rv;
      } else {
#pragma unroll
        for (int g = 0; g < 4; ++g) {
          const int gm = m0 + wm * 64 + i * 16 + quad * 4 + g;
          float v = acc[i][j][g] + bj[j];
          if (MODE == 0) {
            if (gn < 1024) v *= SCL;   // fold softmax scale into Q (pre-round: free)
            ((unsigned short*)Cp)[(size_t)gm * 2048 + gn] = f2bf(v);
          } else {
            ((float*)Cp)[(size_t)gm * N + gn] = v;
          }
        }
      }
    }
  }
}

// ---------------- GEMM, 128x64 tile (proj: 512 blocks = 2/CU), same pipeline ----------------
__global__ __launch_bounds__(256) void gemm_n64(
    const unsigned short* __restrict__ A,
    const unsigned short* __restrict__ Bt,
    const float* __restrict__ bias,
    float* __restrict__ Cp, int M, int N, int K, int lda)
{
  __shared__ __align__(16) unsigned short sA[2][128 * 32];
  __shared__ __align__(16) unsigned short sB[2][64 * 32];
  const int tid = threadIdx.x;
  const int w = tid >> 6, l = tid & 63, ln = l & 15, quad = l >> 4;
  const int wm = w >> 1, wn = w & 1;
  const int m0 = blockIdx.y * 128, n0 = blockIdx.x * 64;
  f32x4 acc[4][2] = {};

  const int elem0 = tid * 8;
  const int ar0 = elem0 >> 5, ac0 = elem0 & 31;
  const int ar1 = (2048 + elem0) >> 5, ac1 = ac0;

  // prologue: stage k0=0 into buf 0
  async16(A  + (size_t)(m0 + ar0) * lda + ac0, &sA[0][w * 512]);
  async16(A  + (size_t)(m0 + ar1) * lda + ac1, &sA[0][2048 + w * 512]);
  async16(Bt + (size_t)(n0 + ar0) * K   + ac0, &sB[0][w * 512]);
  __syncthreads();

  int buf = 0;
  for (int k0 = 0; k0 < K; k0 += 32, buf ^= 1) {
    if (k0 + 32 < K) {
      const int nb = buf ^ 1, kn = k0 + 32;
      async16(A  + (size_t)(m0 + ar0) * lda + kn + ac0, &sA[nb][w * 512]);
      async16(A  + (size_t)(m0 + ar1) * lda + kn + ac1, &sA[nb][2048 + w * 512]);
      async16(Bt + (size_t)(n0 + ar0) * K   + kn + ac0, &sB[nb][w * 512]);
    }

    bf16x8 af[4], bfr[2];
#pragma unroll
    for (int i = 0; i < 4; i++)
      af[i] = *(const bf16x8*)&sA[buf][(wm * 64 + i * 16 + ln) * 32 + quad * 8];
#pragma unroll
    for (int j = 0; j < 2; j++)
      bfr[j] = *(const bf16x8*)&sB[buf][(wn * 32 + j * 16 + ln) * 32 + quad * 8];
#pragma unroll
    for (int i = 0; i < 4; i++)
#pragma unroll
      for (int j = 0; j < 2; j++)
        acc[i][j] = __builtin_amdgcn_mfma_f32_16x16x32_bf16(af[i], bfr[j], acc[i][j], 0, 0, 0);

    __syncthreads();
  }

  float bj[2];
#pragma unroll
  for (int j = 0; j < 2; j++) bj[j] = bias[n0 + wn * 32 + j * 16 + ln];

#pragma unroll
  for (int i = 0; i < 4; i++)
#pragma unroll
    for (int g = 0; g < 4; ++g) {
      const int gm = m0 + wm * 64 + i * 16 + quad * 4 + g;
#pragma unroll
      for (int j = 0; j < 2; j++) {
        const int gn = n0 + wn * 32 + j * 16 + ln;
        Cp[(size_t)gm * N + gn] = acc[i][j][g] + bj[j];
      }
    }
}

// ---------------- Flash attention (causal), D=64, 2 parity groups ----------------
// (round-7 best-measured version, verbatim: ~43us)
// 512 thr = TWO independent 4-wave groups per block, each running the verified
// attn32q machine (32x32 S^T MFMA, in-register cvt_pk/permlane32_swap softmax,
// double/triple-buffered staging, PV-lag-1). Groups split k-tiles by PARITY
// (additive partials under STATIC softmax). 2 waves/SIMD with independent work.
// exp2f -> raw v_exp_f32. {p,15-p} pairing; grid (8,32) = 256 blocks = 1/CU.
__global__ __launch_bounds__(512) void attn2g(
    unsigned short* __restrict__ QK, const unsigned short* __restrict__ Vt)
{
  __shared__ __align__(16) unsigned short kt[2][2][64 * 72];  // [grp][buf][key][d]
  __shared__ __align__(16) unsigned short vt[2][3][64 * 72];  // [grp][buf][d][key]
  __shared__ float Ox[4][2][16][64];                          // [wg][dg][rr][lane]
  __shared__ float Lx[4][64];
  const int pair = blockIdx.x, bh = blockIdx.y;
  const int b = bh >> 4, h = bh & 15;
  const int tid = threadIdx.x;
  const int grp = tid >> 8, gtid = tid & 255;                 // waves 0-3 / 4-7
  const int wg = (tid >> 6) & 3, l = tid & 63;
  const int c = l & 31, h2 = l >> 5;
  unsigned short*       Qp = QK + (size_t)b * TT * 2048 + h * DD;
  const unsigned short* Kp = QK + (size_t)b * TT * 2048 + CC + h * DD;
  const unsigned short* Vh = Vt + (size_t)bh * DD * TT;
  const int si0 = gtid >> 3, so = (gtid & 7) * 8;             // group stages 64x64

  for (int ph = 0; ph < 2; ++ph) {
    const int qt = ph ? 15 - pair : pair;
    const int qbase = qt * 128 + wg * 32;                     // wave's first q-row
    const int qm = qbase + c - 4 * h2;                        // mask helper (verified)
    bf16x8 qv[4];
#pragma unroll
    for (int ds = 0; ds < 4; ++ds)                            // Q B-operand frags
      qv[ds] = *(const bf16x8*)&Qp[(size_t)(qbase + c) * 2048 + ds * 16 + h2 * 8];

    f32x16 oacc[2] = {};
    bf16x8 pA[4] = {};
    float lsum = 0.0f;
    const int nslot = qt + 1;                                 // tiles per group
    int vm1 = 2, v0 = 0, vp1 = 1;

    __syncthreads();                                          // prior phase done
#pragma unroll
    for (int r = 0; r < 2; ++r) {                             // stage kb=grp -> buf 0
      const int si = si0 + 32 * r;
      *(short8*)&kt[grp][0][si * 72 + so] =
          *(const short8*)&Kp[(size_t)(grp * 64 + si) * 2048 + so];
      *(short8*)&vt[grp][0][si * 72 + so] =
          *(const short8*)&Vh[(size_t)si * TT + grp * 64 + so];
    }
    __syncthreads();                                          // buf0 visible

    for (int slot = 0; slot < nslot; ++slot) {
      const int kb = 2 * slot + grp;                          // this group's tile
      const int ck = slot & 1;
      short8 pk[2], pv[2];
      if (slot + 1 < nslot) {                                 // prefetch kb+2 -> regs
        const int kbn = kb + 2;
#pragma unroll
        for (int r = 0; r < 2; ++r) {
          const int si = si0 + 32 * r;
          pk[r] = *(const short8*)&Kp[(size_t)(kbn * 64 + si) * 2048 + so];
          pv[r] = *(const short8*)&Vh[(size_t)si * TT + kbn * 64 + so];
        }
      }
      const bool qk_act = (kb * 64 <= qbase + 31);            // wave-uniform
      f32x16 sacc[2];
      if (qk_act) {                                           // S^T(kb) = K * Q^T
#pragma unroll
        for (int kg = 0; kg < 2; ++kg) {
          f32x16 sa = {};
#pragma unroll
          for (int ds = 0; ds < 4; ++ds) {
            bf16x8 kf = *(const bf16x8*)&kt[grp][ck][(kg * 32 + c) * 72 + ds * 16 + h2 * 8];
            sa = __builtin_amdgcn_mfma_f32_32x32x16_bf16(kf, qv[ds], sa, 0, 0, 0);
          }
          sacc[kg] = sa;
        }
      }
      if (slot > 0 && (kb - 2) * 64 <= qbase + 31) {          // PV(kb-2), overlaps SM
        const unsigned short* vp = vt[grp][vm1];
#pragma unroll
        for (int dg = 0; dg < 2; ++dg)
#pragma unroll
          for (int ks = 0; ks < 4; ++ks) {
            bf16x8 vf = *(const bf16x8*)&vp[(dg * 32 + c) * 72 + ks * 16 + h2 * 8];
            oacc[dg] = __builtin_amdgcn_mfma_f32_32x32x16_bf16(pA[ks], vf, oacc[dg], 0, 0, 0);
          }
      }
      if (qk_act) {
        const bool need_mask = (kb * 64 + 63 > qbase);        // diagonal tiles only
        float pe[2][16];
#pragma unroll
        for (int kg = 0; kg < 2; ++kg)
#pragma unroll
          for (int rr = 0; rr < 16; ++rr) {
            float sv = sacc[kg][rr];
            if (need_mask) {
              const int krel = kb * 64 + kg * 32 + (rr & 3) + 8 * (rr >> 2);
              if (krel > qm) sv = NEGBIG;                     // key > q -> masked
            }
            float e;
            asm("v_exp_f32 %0, %1" : "=v"(e) : "v"(sv));      // 2^sv; 2^-1e30 = 0
            pe[kg][rr] = e;
            lsum += e;
          }
        // pack P^T pairs to bf16, redistribute to PV A-frags (round-3/4-verified)
        unsigned W0[2][4], W1[2][4];
#pragma unroll
        for (int kg = 0; kg < 2; ++kg)
#pragma unroll
          for (int r4 = 0; r4 < 4; ++r4) {
            asm("v_cvt_pk_bf16_f32 %0, %1, %2"
                : "=v"(W0[kg][r4]) : "v"(pe[kg][4 * r4 + 0]), "v"(pe[kg][4 * r4 + 1]));
            asm("v_cvt_pk_bf16_f32 %0, %1, %2"
                : "=v"(W1[kg][r4]) : "v"(pe[kg][4 * r4 + 2]), "v"(pe[kg][4 * r4 + 3]));
          }
#pragma unroll
        for (int ks = 0; ks < 4; ++ks) {
          const int kg = ks >> 1, sel = ks & 1;
          unsigned a0 = W0[kg][2 * sel], b0 = W0[kg][2 * sel + 1];
          unsigned a1 = W1[kg][2 * sel], b1 = W1[kg][2 * sel + 1];
          asm("v_permlane32_swap_b32 %0, %1" : "+v"(a0), "+v"(b0));
          asm("v_permlane32_swap_b32 %0, %1" : "+v"(a1), "+v"(b1));
          unsigned wds[4] = {a0, a1, b0, b1};                 // keys e01,e23,e45,e67
          pA[ks] = *(const bf16x8*)wds;
        }
      }
      if (slot + 1 < nslot) {                                 // stage kb+2
#pragma unroll
        for (int r = 0; r < 2; ++r) {
          const int si = si0 + 32 * r;
          *(short8*)&kt[grp][1 - ck][si * 72 + so] = pk[r];
          *(short8*)&vt[grp][vp1][si * 72 + so] = pv[r];
        }
      }
      __syncthreads();                                        // one barrier per slot
      const int t_ = vm1; vm1 = v0; v0 = vp1; vp1 = t_;       // rotate V buffers
    }
    // drain: PV of this group's last tile (vm1 == its V after final rotation)
    const int kb_last = 2 * qt + grp;
    if (kb_last * 64 <= qbase + 31) {
      const unsigned short* vp = vt[grp][vm1];
#pragma unroll
      for (int dg = 0; dg < 2; ++dg)
#pragma unroll
        for (int ks = 0; ks < 4; ++ks) {
          bf16x8 vf = *(const bf16x8*)&vp[(dg * 32 + c) * 72 + ks * 16 + h2 * 8];
          oacc[dg] = __builtin_amdgcn_mfma_f32_32x32x16_bf16(pA[ks], vf, oacc[dg], 0, 0, 0);
        }
    }
    // ---- merge the two parity groups (additive partials), normalize, store ----
    lsum += __shfl_xor(lsum, 32);                             // l partial for q=c
    if (grp == 1) {
#pragma unroll
      for (int dg = 0; dg < 2; ++dg)
#pragma unroll
        for (int rr = 0; rr < 16; ++rr) Ox[wg][dg][rr][l] = oacc[dg][rr];
      Lx[wg][l] = lsum;
    }
    __syncthreads();
    if (grp == 0) {
      const float inv = 1.0f / (lsum + Lx[wg][l]);            // valid for q=c
#pragma unroll
      for (int dg = 0; dg < 2; ++dg)
#pragma unroll
        for (int rr = 0; rr < 16; ++rr) oacc[dg][rr] += Ox[wg][dg][rr][l];
#pragma unroll
      for (int rr = 0; rr < 16; ++rr) {
        const int q_rel = (rr & 3) + 8 * (rr >> 2) + 4 * h2;
        const float iq = __shfl(inv, q_rel);
        const size_t trow = qbase + q_rel;
#pragma unroll
        for (int dg = 0; dg < 2; ++dg)
          Qp[trow * 2048 + dg * 32 + c] = f2bf(oacc[dg][rr] * iq);
      }
    }
  }
}

extern "C" void kernel_launch(void* const* d_in, const int* in_sizes, int n_in,
                              void* d_out, int out_size, void* d_ws, size_t ws_size,
                              hipStream_t stream)
{
  (void)in_sizes; (void)n_in; (void)out_size; (void)ws_size;
  const float* x     = (const float*)d_in[0];   // [B,T,C] fp32
  const float* Wqkv  = (const float*)d_in[1];   // [C,3C]
  const float* bqkv  = (const float*)d_in[2];   // [3C]
  const float* Wproj = (const float*)d_in[3];   // [C,C]
  const float* bproj = (const float*)d_in[4];   // [C]

  unsigned short* QK     = (unsigned short*)d_ws;            // [4096][2048] bf16, 16 MB
  unsigned short* WqkvT  = QK + (size_t)4096 * 2048;         // [3072][1024] bf16, 6 MB
  unsigned short* WprojT = WqkvT;                            // aliases (after GEMM1)
  unsigned short* Vt = (unsigned short*)d_out;               // scratch in d_out, 8 MB
  unsigned short* xb = Vt + (size_t)32 * 64 * 2048;          // scratch in d_out, 8 MB

  cvt_bf16<<<dim3(4096 * 1024 / 8 / 256), 256, 0, stream>>>(x, xb, 4096 * 1024 / 8);
  transpose_cvt<<<dim3(C3 / 64, CC / 64), 256, 0, stream>>>(Wqkv, WqkvT, CC, C3);
  gemm_bt<0><<<dim3(C3 / 128, 4096 / 128), 256, 0, stream>>>(
      xb, WqkvT, bqkv, QK, Vt, 4096, C3, CC, CC);
  transpose_cvt<<<dim3(CC / 64, CC / 64), 256, 0, stream>>>(Wproj, WprojT, CC, CC);
  attn2g<<<dim3(8, 2 * HH), 512, 0, stream>>>(QK, Vt);
  gemm_n64<<<dim3(CC / 64, 4096 / 128), 256, 0, stream>>>(
      QK, WprojT, bproj, (float*)d_out, 4096, CC, CC, 2048);
}